// Round 8
// baseline (73.713 us; speedup 1.0000x reference)
//
#include <hip/hip_runtime.h>
#include <hip/hip_bf16.h>

#define BATCHN 16
#define SEQ 4096
#define HIDDEN 128
#define STATE 256
#define MTOT (BATCHN*SEQ)    // 65536
#define NCHUNK 64
#define LCHUNK 64            // SEQ / NCHUNK
#define NTILE (MTOT/64)      // 1024 tiles

typedef __bf16 bf16;
typedef __bf16 bf16x4 __attribute__((ext_vector_type(4)));
typedef __bf16 bf16x8 __attribute__((ext_vector_type(8)));
typedef float f32x4 __attribute__((ext_vector_type(4)));

__device__ __forceinline__ void scan_params(const float* __restrict__ A_diag,
        const float* __restrict__ steps, int n,
        float& m11, float& m12, float& m21, float& m22, float& c1, float& c2) {
    float st = 1.0f / (1.0f + expf(-steps[n]));
    float A  = fmaxf(A_diag[n], 0.0f);
    float s2A = st * st * A;
    float schur = 1.0f / (1.0f + s2A);
    m11 = 1.0f - s2A * schur;
    m12 = -st * A * schur;
    m21 = st * schur;
    m22 = schur;
    c1 = m11 * st;
    c2 = m21 * st;
}

// load 8 consecutive fp32 -> bf16x8 fragment (L2/L3-hot B/C panels)
__device__ __forceinline__ bf16x8 load_frag_f32(const float* __restrict__ src) {
    float4 a = *reinterpret_cast<const float4*>(src);
    float4 b = *reinterpret_cast<const float4*>(src + 4);
    bf16x8 r = { (bf16)a.x, (bf16)a.y, (bf16)a.z, (bf16)a.w,
                 (bf16)b.x, (bf16)b.y, (bf16)b.z, (bf16)b.w };
    return r;
}

// ---------------- K1: stage x (aliased) -> GEMM1 -> Bu store -> scanA -> cs ----------------
// LDS = bu only (34 KB): x tile staged into bu cols [0,128) (A-reads complete
// before acc->bu overwrite, barrier-protected). 4 blocks/CU, grid 1024 = 4x256 CU.
__global__ __launch_bounds__(256, 4) void k1_gemm_scanA(const float* __restrict__ x,
        const float* __restrict__ A_diag, const float* __restrict__ steps,
        const float* __restrict__ Bm, float* __restrict__ cs,
        bf16* __restrict__ Bu_g) {
    __shared__ bf16 bu[64][264];
    const int tid = threadIdx.x;
    const int bid = blockIdx.x;
    const int m0 = bid * 64;
    const int wid = tid >> 6, lane = tid & 63;
    const int lr = lane & 15, lk = (lane >> 4) * 8;
    const int n0 = wid * 64;
    const int mrow = (lane >> 4) * 4;

    // stage x (fp32 -> bf16) into bu cols [0,128)
    #pragma unroll
    for (int p = 0; p < 8; ++p) {
        int flat = p * 256 + tid;                // 64 rows x 32 float4
        int row = flat >> 5, c4 = flat & 31;
        float4 v = *reinterpret_cast<const float4*>(&x[(size_t)(m0 + row) * HIDDEN + c4 * 4]);
        bf16x4 w = { (bf16)v.x, (bf16)v.y, (bf16)v.z, (bf16)v.w };
        *reinterpret_cast<bf16x4*>(&bu[row][c4 * 4]) = w;
    }
    __syncthreads();

    // GEMM1: Bu = x @ B^T (A from bu cols [0,128), B inline fp32->bf16)
    f32x4 acc[4][4];
    #pragma unroll
    for (int i = 0; i < 4; ++i)
        #pragma unroll
        for (int j = 0; j < 4; ++j) acc[i][j] = f32x4{0.f, 0.f, 0.f, 0.f};
    #pragma unroll
    for (int ks = 0; ks < 4; ++ks) {
        int k = ks * 32 + lk;
        bf16x8 a[4], bfr[4];
        #pragma unroll
        for (int mf = 0; mf < 4; ++mf)
            a[mf] = *reinterpret_cast<const bf16x8*>(&bu[mf * 16 + lr][k]);
        #pragma unroll
        for (int nf = 0; nf < 4; ++nf)
            bfr[nf] = load_frag_f32(&Bm[(size_t)(n0 + nf * 16 + lr) * HIDDEN + k]);
        #pragma unroll
        for (int mf = 0; mf < 4; ++mf)
            #pragma unroll
            for (int nf = 0; nf < 4; ++nf)
                acc[mf][nf] = __builtin_amdgcn_mfma_f32_16x16x32_bf16(a[mf], bfr[nf], acc[mf][nf], 0, 0, 0);
    }
    __syncthreads();                              // all A-frag reads done before overwrite
    #pragma unroll
    for (int mf = 0; mf < 4; ++mf)
        #pragma unroll
        for (int nf = 0; nf < 4; ++nf)
            #pragma unroll
            for (int r = 0; r < 4; ++r)
                bu[mf * 16 + mrow + r][n0 + nf * 16 + lr] = (bf16)acc[mf][nf][r];

    const int n = tid;
    float m11, m12, m21, m22, c1, c2;
    scan_params(A_diag, steps, n, m11, m12, m21, m22, c1, c2);
    __syncthreads();

    // coalesced Bu store (issues first; drains under the scan)
    #pragma unroll
    for (int p = 0; p < 8; ++p) {
        int flat = p * 256 + tid;                // 64 rows x 32 chunks of 8 bf16
        int row = flat >> 5, c8 = flat & 31;
        bf16x8 v = *reinterpret_cast<const bf16x8*>(&bu[row][c8 * 8]);
        *reinterpret_cast<bf16x8*>(&Bu_g[((size_t)(m0 + row)) * STATE + c8 * 8]) = v;
    }

    // local scan (phase A), thread = state n -> inclusive chunk summary
    float s1 = 0.f, s2 = 0.f;
    #pragma unroll 8
    for (int t = 0; t < LCHUNK; ++t) {
        float v = (float)bu[t][n];
        float ns1 = fmaf(m11, s1, fmaf(m12, s2, c1 * v));
        float ns2 = fmaf(m21, s1, fmaf(m22, s2, c2 * v));
        s1 = ns1; s2 = ns2;
    }
    size_t base = ((size_t)bid * 2) * STATE + n;  // bid == batch*NCHUNK+chunk
    cs[base] = s1;
    cs[base + STATE] = s2;
}

// ---------------- comb: Kogge-Stone over chunks, lane = chunk ----------------
// grid = BATCHN*4 blocks x 256 thr; thread = (chunk c = tid&63, wave nsub = tid>>6).
// Each block handles one batch x 64 n-values (16 iterations of 4 n). In-place:
// cs slot (b,c,n) becomes EXCLUSIVE prefix (init state of chunk c).
__global__ __launch_bounds__(256) void scan_comb_ks(float* __restrict__ cs,
        const float* __restrict__ A_diag, const float* __restrict__ steps) {
    const int c    = threadIdx.x & 63;            // chunk = lane
    const int nsub = threadIdx.x >> 6;            // 0..3
    const int b    = blockIdx.x >> 2;
    const int nb   = blockIdx.x & 3;              // n-range [nb*64, nb*64+64)
    #pragma nounroll
    for (int i = 0; i < 16; ++i) {
        const int n = nb * 64 + i * 4 + nsub;
        float m11, m12, m21, m22, cu1, cu2;
        scan_params(A_diag, steps, n, m11, m12, m21, m22, cu1, cu2);
        // M64 = M^64 via squaring
        float p11 = m11, p12 = m12, p21 = m21, p22 = m22;
        #pragma unroll
        for (int r = 0; r < 6; ++r) {
            float q11 = p11 * p11 + p12 * p21;
            float q12 = p11 * p12 + p12 * p22;
            float q21 = p21 * p11 + p22 * p21;
            float q22 = p21 * p12 + p22 * p22;
            p11 = q11; p12 = q12; p21 = q21; p22 = q22;
        }
        size_t base = ((size_t)(b * NCHUNK + c) * 2) * STATE + n;
        float V1 = cs[base], V2 = cs[base + STATE];
        // Kogge-Stone inclusive scan under affine composition; P_r = M64^(2^r)
        #pragma unroll
        for (int r = 0; r < 6; ++r) {
            int d = 1 << r;
            float U1 = __shfl_up(V1, d, 64);
            float U2 = __shfl_up(V2, d, 64);
            if (c >= d) {
                V1 = fmaf(p11, U1, fmaf(p12, U2, V1));
                V2 = fmaf(p21, U1, fmaf(p22, U2, V2));
            }
            float q11 = p11 * p11 + p12 * p21;
            float q12 = p11 * p12 + p12 * p22;
            float q21 = p21 * p11 + p22 * p21;
            float q22 = p21 * p12 + p22 * p22;
            p11 = q11; p12 = q12; p21 = q21; p22 = q22;
        }
        // exclusive = inclusive of c-1 (zero for c==0)
        float E1 = __shfl_up(V1, 1, 64);
        float E2 = __shfl_up(V2, 1, 64);
        if (c == 0) { E1 = 0.f; E2 = 0.f; }
        cs[base] = E1;
        cs[base + STATE] = E2;
    }
}

// ---------------- K2: stage Bu + scanC + GEMM2 + D*x ----------------
// LDS 34 KB -> 4 blocks/CU. cs holds exclusive prefix (kernel boundary = visible).
__global__ __launch_bounds__(256, 4) void k2_scan_gemm(const bf16* __restrict__ Bu_g,
        const float* __restrict__ x, const float* __restrict__ A_diag,
        const float* __restrict__ steps, const float* __restrict__ Cm,
        const float* __restrict__ cs, const float* __restrict__ Dv,
        float* __restrict__ out) {
    __shared__ bf16 bu[64][264];                  // aliased as fp32 [64][132] for epilogue
    float (*ldsF)[132] = reinterpret_cast<float(*)[132]>(&bu[0][0]);
    const int tid = threadIdx.x;
    const int bid = blockIdx.x;
    const int m0 = bid * 64;
    const int wid = tid >> 6, lane = tid & 63;
    const int lr = lane & 15, lk = (lane >> 4) * 8;
    const int h0 = wid * 32;
    const int n = tid;
    const int mrow = (lane >> 4) * 4;

    // stage Bu tile (coalesced 16B loads)
    #pragma unroll
    for (int p = 0; p < 8; ++p) {
        int flat = p * 256 + tid;
        int row = flat >> 5, c8 = flat & 31;
        bf16x8 v = *reinterpret_cast<const bf16x8*>(&Bu_g[((size_t)(m0 + row)) * STATE + c8 * 8]);
        *reinterpret_cast<bf16x8*>(&bu[row][c8 * 8]) = v;
    }

    // scan params + exclusive init state (hides under Bu-stage vmcnt)
    float m11, m12, m21, m22, c1, c2;
    scan_params(A_diag, steps, n, m11, m12, m21, m22, c1, c2);
    size_t cbase = ((size_t)bid * 2) * STATE + n;
    float s1 = cs[cbase], s2 = cs[cbase + STATE];
    __syncthreads();

    // scanC with true init state; overwrite bu with y (bf16)
    #pragma unroll 8
    for (int t = 0; t < LCHUNK; ++t) {
        float v = (float)bu[t][n];
        float ns1 = fmaf(m11, s1, fmaf(m12, s2, c1 * v));
        float ns2 = fmaf(m21, s1, fmaf(m22, s2, c2 * v));
        s1 = ns1; s2 = ns2;
        bu[t][n] = (bf16)s2;
    }
    __syncthreads();

    // GEMM2: y @ C^T (inline fp32->bf16 C frags)
    f32x4 acc2[4][2];
    #pragma unroll
    for (int i = 0; i < 4; ++i) {
        acc2[i][0] = f32x4{0.f, 0.f, 0.f, 0.f};
        acc2[i][1] = f32x4{0.f, 0.f, 0.f, 0.f};
    }
    #pragma unroll
    for (int ks = 0; ks < 8; ++ks) {
        int k = ks * 32 + lk;
        bf16x8 a[4], cfr[2];
        #pragma unroll
        for (int mf = 0; mf < 4; ++mf)
            a[mf] = *reinterpret_cast<const bf16x8*>(&bu[mf * 16 + lr][k]);
        #pragma unroll
        for (int hf = 0; hf < 2; ++hf)
            cfr[hf] = load_frag_f32(&Cm[(size_t)(h0 + hf * 16 + lr) * STATE + k]);
        #pragma unroll
        for (int mf = 0; mf < 4; ++mf)
            #pragma unroll
            for (int hf = 0; hf < 2; ++hf)
                acc2[mf][hf] = __builtin_amdgcn_mfma_f32_16x16x32_bf16(a[mf], cfr[hf], acc2[mf][hf], 0, 0, 0);
    }
    __syncthreads();                              // all bu reads done before fp32 reuse
    #pragma unroll
    for (int mf = 0; mf < 4; ++mf)
        #pragma unroll
        for (int hf = 0; hf < 2; ++hf)
            #pragma unroll
            for (int r = 0; r < 4; ++r)
                ldsF[mf * 16 + mrow + r][h0 + hf * 16 + lr] = acc2[mf][hf][r];
    __syncthreads();

    // coalesced epilogue: out = ldsF + D*x
    #pragma unroll
    for (int p = 0; p < 8; ++p) {
        int flat = p * 256 + tid;
        int row = flat >> 5, c4 = flat & 31;
        float4 xv = *reinterpret_cast<const float4*>(&x[(size_t)(m0 + row) * HIDDEN + c4 * 4]);
        float4 f = *reinterpret_cast<const float4*>(&ldsF[row][c4 * 4]);
        float4 d = *reinterpret_cast<const float4*>(&Dv[c4 * 4]);
        float4 o;
        o.x = f.x + d.x * xv.x;
        o.y = f.y + d.y * xv.y;
        o.z = f.z + d.z * xv.z;
        o.w = f.w + d.w * xv.w;
        *reinterpret_cast<float4*>(&out[(size_t)(m0 + row) * HIDDEN + c4 * 4]) = o;
    }
}

extern "C" void kernel_launch(void* const* d_in, const int* in_sizes, int n_in,
                              void* d_out, int out_size, void* d_ws, size_t ws_size,
                              hipStream_t stream) {
    const float* x      = (const float*)d_in[0];
    const float* A_diag = (const float*)d_in[1];
    const float* steps  = (const float*)d_in[2];
    const float* Bm     = (const float*)d_in[3];
    const float* Cm     = (const float*)d_in[4];
    const float* Dv     = (const float*)d_in[5];
    float* out = (float*)d_out;

    char* ws = (char*)d_ws;
    const size_t CS_BYTES = (size_t)NTILE * 2 * STATE * 4;   // 2 MB
    float* cs   = (float*)ws;
    bf16*  Bu_g = (bf16*)(ws + CS_BYTES);                    // 32 MB

    hipLaunchKernelGGL(k1_gemm_scanA, dim3(NTILE), dim3(256), 0, stream,
                       x, A_diag, steps, Bm, cs, Bu_g);
    hipLaunchKernelGGL(scan_comb_ks, dim3(BATCHN * 4), dim3(256), 0, stream,
                       cs, A_diag, steps);
    hipLaunchKernelGGL(k2_scan_gemm, dim3(NTILE), dim3(256), 0, stream,
                       Bu_g, x, A_diag, steps, Cm, cs, Dv, out);
}

// Round 9
// 61.906 us; speedup vs baseline: 1.1907x; 1.1907x over previous
//
#include <hip/hip_runtime.h>
#include <hip/hip_bf16.h>

#define BATCHN 16
#define SEQ 4096
#define HIDDEN 128
#define STATE 256
#define MTOT (BATCHN*SEQ)    // 65536
#define NCHUNK 64
#define LCHUNK 64            // SEQ / NCHUNK
#define NTILE (MTOT/64)      // 1024 tiles

typedef __bf16 bf16;
typedef __bf16 bf16x4 __attribute__((ext_vector_type(4)));
typedef __bf16 bf16x8 __attribute__((ext_vector_type(8)));
typedef float f32x4 __attribute__((ext_vector_type(4)));

__device__ __forceinline__ void scan_params(const float* __restrict__ A_diag,
        const float* __restrict__ steps, int n,
        float& m11, float& m12, float& m21, float& m22, float& c1, float& c2) {
    float st = 1.0f / (1.0f + expf(-steps[n]));
    float A  = fmaxf(A_diag[n], 0.0f);
    float s2A = st * st * A;
    float schur = 1.0f / (1.0f + s2A);
    m11 = 1.0f - s2A * schur;
    m12 = -st * A * schur;
    m21 = st * schur;
    m22 = schur;
    c1 = m11 * st;
    c2 = m21 * st;
}

// ---------------- setup: bf16 copies of B, C (1 load per frag later) ----------------
__global__ __launch_bounds__(256) void setup_k(const float* __restrict__ Bm,
        const float* __restrict__ Cm, bf16* __restrict__ Bbf, bf16* __restrict__ Cbf) {
    int idx = blockIdx.x * 256 + threadIdx.x;   // grid 128 -> 32768 = STATE*HIDDEN
    Bbf[idx] = (bf16)Bm[idx];
    Cbf[idx] = (bf16)Cm[idx];
}

// ---------------- K1: B-frag preload -> stage x -> GEMM1 -> Bu store -> scanA ----------------
// 51 KB LDS, bounds(256,3) -> VGPR cap ~168: 64 frag + 64 acc fit, no spill.
__global__ __launch_bounds__(256, 3) void k1_gemm_scanA(const float* __restrict__ x,
        const bf16* __restrict__ Bbf, const float* __restrict__ A_diag,
        const float* __restrict__ steps, float* __restrict__ cs,
        bf16* __restrict__ Bu_g) {
    __shared__ bf16 xl[64][136];
    __shared__ bf16 bu[64][264];
    const int tid = threadIdx.x;
    const int bid = blockIdx.x;
    const int m0 = bid * 64;
    const int wid = tid >> 6, lane = tid & 63;
    const int lr = lane & 15, lk = (lane >> 4) * 8;
    const int n0 = wid * 64;
    const int mrow = (lane >> 4) * 4;

    // T14: issue ALL 16 B-frag loads now (straight-line, const-indexed array ->
    // registers; NOT passed to any function — R3's spill was pointer-decay).
    // They drain while x is staged below.
    bf16x8 bfr[4][4];
    #pragma unroll
    for (int ks = 0; ks < 4; ++ks)
        #pragma unroll
        for (int nf = 0; nf < 4; ++nf)
            bfr[ks][nf] = *reinterpret_cast<const bf16x8*>(
                &Bbf[(size_t)(n0 + nf * 16 + lr) * HIDDEN + ks * 32 + lk]);

    // stage x (fp32 -> bf16)
    #pragma unroll
    for (int p = 0; p < 8; ++p) {
        int flat = p * 256 + tid;                // 64 rows x 32 float4
        int row = flat >> 5, c4 = flat & 31;
        float4 v = *reinterpret_cast<const float4*>(&x[(size_t)(m0 + row) * HIDDEN + c4 * 4]);
        bf16x4 w = { (bf16)v.x, (bf16)v.y, (bf16)v.z, (bf16)v.w };
        *reinterpret_cast<bf16x4*>(&xl[row][c4 * 4]) = w;
    }
    __syncthreads();

    // GEMM1: Bu = x @ B^T — no global loads inside the MFMA loop
    f32x4 acc[4][4];
    #pragma unroll
    for (int i = 0; i < 4; ++i)
        #pragma unroll
        for (int j = 0; j < 4; ++j) acc[i][j] = f32x4{0.f, 0.f, 0.f, 0.f};
    #pragma unroll
    for (int ks = 0; ks < 4; ++ks) {
        int k = ks * 32 + lk;
        bf16x8 a[4];
        #pragma unroll
        for (int mf = 0; mf < 4; ++mf)
            a[mf] = *reinterpret_cast<const bf16x8*>(&xl[mf * 16 + lr][k]);
        #pragma unroll
        for (int mf = 0; mf < 4; ++mf)
            #pragma unroll
            for (int nf = 0; nf < 4; ++nf)
                acc[mf][nf] = __builtin_amdgcn_mfma_f32_16x16x32_bf16(a[mf], bfr[ks][nf], acc[mf][nf], 0, 0, 0);
    }
    #pragma unroll
    for (int mf = 0; mf < 4; ++mf)
        #pragma unroll
        for (int nf = 0; nf < 4; ++nf)
            #pragma unroll
            for (int r = 0; r < 4; ++r)
                bu[mf * 16 + mrow + r][n0 + nf * 16 + lr] = (bf16)acc[mf][nf][r];

    const int n = tid;
    float m11, m12, m21, m22, c1, c2;
    scan_params(A_diag, steps, n, m11, m12, m21, m22, c1, c2);
    __syncthreads();

    // coalesced Bu store (issues first; drains under the scan)
    #pragma unroll
    for (int p = 0; p < 8; ++p) {
        int flat = p * 256 + tid;                // 64 rows x 32 chunks of 8 bf16
        int row = flat >> 5, c8 = flat & 31;
        bf16x8 v = *reinterpret_cast<const bf16x8*>(&bu[row][c8 * 8]);
        *reinterpret_cast<bf16x8*>(&Bu_g[((size_t)(m0 + row)) * STATE + c8 * 8]) = v;
    }

    // local scan (phase A), thread = state n -> inclusive chunk summary
    float s1 = 0.f, s2 = 0.f;
    #pragma unroll 8
    for (int t = 0; t < LCHUNK; ++t) {
        float v = (float)bu[t][n];
        float ns1 = fmaf(m11, s1, fmaf(m12, s2, c1 * v));
        float ns2 = fmaf(m21, s1, fmaf(m22, s2, c2 * v));
        s1 = ns1; s2 = ns2;
    }
    size_t base = ((size_t)bid * 2) * STATE + n;  // bid == batch*NCHUNK+chunk
    cs[base] = s1;
    cs[base + STATE] = s2;
}

// ---------------- comb: Kogge-Stone over chunks, lane = chunk ----------------
// In-place: cs slot (b,c,n) becomes EXCLUSIVE prefix. unroll 4 -> strided cs
// loads of consecutive iterations overlap.
__global__ __launch_bounds__(256) void scan_comb_ks(float* __restrict__ cs,
        const float* __restrict__ A_diag, const float* __restrict__ steps) {
    const int c    = threadIdx.x & 63;            // chunk = lane
    const int nsub = threadIdx.x >> 6;            // 0..3
    const int b    = blockIdx.x >> 2;
    const int nb   = blockIdx.x & 3;              // n-range [nb*64, nb*64+64)
    #pragma unroll 4
    for (int i = 0; i < 16; ++i) {
        const int n = nb * 64 + i * 4 + nsub;
        float m11, m12, m21, m22, cu1, cu2;
        scan_params(A_diag, steps, n, m11, m12, m21, m22, cu1, cu2);
        float p11 = m11, p12 = m12, p21 = m21, p22 = m22;
        #pragma unroll
        for (int r = 0; r < 6; ++r) {             // M^64 via squaring
            float q11 = p11 * p11 + p12 * p21;
            float q12 = p11 * p12 + p12 * p22;
            float q21 = p21 * p11 + p22 * p21;
            float q22 = p21 * p12 + p22 * p22;
            p11 = q11; p12 = q12; p21 = q21; p22 = q22;
        }
        size_t base = ((size_t)(b * NCHUNK + c) * 2) * STATE + n;
        float V1 = cs[base], V2 = cs[base + STATE];
        #pragma unroll
        for (int r = 0; r < 6; ++r) {             // KS inclusive scan
            int d = 1 << r;
            float U1 = __shfl_up(V1, d, 64);
            float U2 = __shfl_up(V2, d, 64);
            if (c >= d) {
                V1 = fmaf(p11, U1, fmaf(p12, U2, V1));
                V2 = fmaf(p21, U1, fmaf(p22, U2, V2));
            }
            float q11 = p11 * p11 + p12 * p21;
            float q12 = p11 * p12 + p12 * p22;
            float q21 = p21 * p11 + p22 * p21;
            float q22 = p21 * p12 + p22 * p22;
            p11 = q11; p12 = q12; p21 = q21; p22 = q22;
        }
        float E1 = __shfl_up(V1, 1, 64);          // exclusive = inclusive of c-1
        float E2 = __shfl_up(V2, 1, 64);
        if (c == 0) { E1 = 0.f; E2 = 0.f; }
        cs[base] = E1;
        cs[base + STATE] = E2;
    }
}

// ---------------- K2: Bu stage + C-frag preload -> scanC -> GEMM2 -> D*x ----------------
// 34 KB LDS, bounds(256,3): C frags (64 VGPR) stay live across the scan.
__global__ __launch_bounds__(256, 3) void k2_scan_gemm(const bf16* __restrict__ Bu_g,
        const float* __restrict__ x, const float* __restrict__ A_diag,
        const float* __restrict__ steps, const bf16* __restrict__ Cbf,
        const float* __restrict__ cs, const float* __restrict__ Dv,
        float* __restrict__ out) {
    __shared__ bf16 bu[64][264];                  // aliased as fp32 [64][132] for epilogue
    float (*ldsF)[132] = reinterpret_cast<float(*)[132]>(&bu[0][0]);
    const int tid = threadIdx.x;
    const int bid = blockIdx.x;
    const int m0 = bid * 64;
    const int wid = tid >> 6, lane = tid & 63;
    const int lr = lane & 15, lk = (lane >> 4) * 8;
    const int h0 = wid * 32;
    const int n = tid;
    const int mrow = (lane >> 4) * 4;

    // stage Bu into regs (issue all 8 loads first)
    bf16x8 sreg[8];
    #pragma unroll
    for (int p = 0; p < 8; ++p) {
        int flat = p * 256 + tid;
        int row = flat >> 5, c8 = flat & 31;
        sreg[p] = *reinterpret_cast<const bf16x8*>(&Bu_g[((size_t)(m0 + row)) * STATE + c8 * 8]);
    }
    // T14: issue ALL 16 C-frag loads now; consumed after the scan
    bf16x8 cfr[8][2];
    #pragma unroll
    for (int ks = 0; ks < 8; ++ks)
        #pragma unroll
        for (int hf = 0; hf < 2; ++hf)
            cfr[ks][hf] = *reinterpret_cast<const bf16x8*>(
                &Cbf[(size_t)(h0 + hf * 16 + lr) * STATE + ks * 32 + lk]);
    // write staged Bu to LDS (waits only on the 8 Bu loads)
    #pragma unroll
    for (int p = 0; p < 8; ++p) {
        int flat = p * 256 + tid;
        int row = flat >> 5, c8 = flat & 31;
        *reinterpret_cast<bf16x8*>(&bu[row][c8 * 8]) = sreg[p];
    }

    float m11, m12, m21, m22, c1, c2;
    scan_params(A_diag, steps, n, m11, m12, m21, m22, c1, c2);
    size_t cbase = ((size_t)bid * 2) * STATE + n;
    float s1 = cs[cbase], s2 = cs[cbase + STATE];
    __syncthreads();

    // scanC with true init state; overwrite bu with y (bf16)
    #pragma unroll 8
    for (int t = 0; t < LCHUNK; ++t) {
        float v = (float)bu[t][n];
        float ns1 = fmaf(m11, s1, fmaf(m12, s2, c1 * v));
        float ns2 = fmaf(m21, s1, fmaf(m22, s2, c2 * v));
        s1 = ns1; s2 = ns2;
        bu[t][n] = (bf16)s2;
    }
    __syncthreads();

    // GEMM2: y @ C^T — no global loads inside the MFMA loop
    f32x4 acc2[4][2];
    #pragma unroll
    for (int i = 0; i < 4; ++i) {
        acc2[i][0] = f32x4{0.f, 0.f, 0.f, 0.f};
        acc2[i][1] = f32x4{0.f, 0.f, 0.f, 0.f};
    }
    #pragma unroll
    for (int ks = 0; ks < 8; ++ks) {
        int k = ks * 32 + lk;
        bf16x8 a[4];
        #pragma unroll
        for (int mf = 0; mf < 4; ++mf)
            a[mf] = *reinterpret_cast<const bf16x8*>(&bu[mf * 16 + lr][k]);
        #pragma unroll
        for (int mf = 0; mf < 4; ++mf)
            #pragma unroll
            for (int hf = 0; hf < 2; ++hf)
                acc2[mf][hf] = __builtin_amdgcn_mfma_f32_16x16x32_bf16(a[mf], cfr[ks][hf], acc2[mf][hf], 0, 0, 0);
    }
    __syncthreads();                              // all bu reads done before fp32 reuse
    #pragma unroll
    for (int mf = 0; mf < 4; ++mf)
        #pragma unroll
        for (int hf = 0; hf < 2; ++hf)
            #pragma unroll
            for (int r = 0; r < 4; ++r)
                ldsF[mf * 16 + mrow + r][h0 + hf * 16 + lr] = acc2[mf][hf][r];
    __syncthreads();

    // coalesced epilogue: out = ldsF + D*x
    #pragma unroll
    for (int p = 0; p < 8; ++p) {
        int flat = p * 256 + tid;
        int row = flat >> 5, c4 = flat & 31;
        float4 xv = *reinterpret_cast<const float4*>(&x[(size_t)(m0 + row) * HIDDEN + c4 * 4]);
        float4 f = *reinterpret_cast<const float4*>(&ldsF[row][c4 * 4]);
        float4 d = *reinterpret_cast<const float4*>(&Dv[c4 * 4]);
        float4 o;
        o.x = f.x + d.x * xv.x;
        o.y = f.y + d.y * xv.y;
        o.z = f.z + d.z * xv.z;
        o.w = f.w + d.w * xv.w;
        *reinterpret_cast<float4*>(&out[(size_t)(m0 + row) * HIDDEN + c4 * 4]) = o;
    }
}

extern "C" void kernel_launch(void* const* d_in, const int* in_sizes, int n_in,
                              void* d_out, int out_size, void* d_ws, size_t ws_size,
                              hipStream_t stream) {
    const float* x      = (const float*)d_in[0];
    const float* A_diag = (const float*)d_in[1];
    const float* steps  = (const float*)d_in[2];
    const float* Bm     = (const float*)d_in[3];
    const float* Cm     = (const float*)d_in[4];
    const float* Dv     = (const float*)d_in[5];
    float* out = (float*)d_out;

    char* ws = (char*)d_ws;
    const size_t CS_BYTES = (size_t)NTILE * 2 * STATE * 4;   // 2 MB
    float* cs   = (float*)ws;
    bf16*  Bbf  = (bf16*)(ws + CS_BYTES);
    bf16*  Cbf  = (bf16*)(ws + CS_BYTES + (size_t)STATE * HIDDEN * 2);
    bf16*  Bu_g = (bf16*)(ws + CS_BYTES + (size_t)STATE * HIDDEN * 4);  // 32 MB

    hipLaunchKernelGGL(setup_k, dim3(128), dim3(256), 0, stream, Bm, Cm, Bbf, Cbf);
    hipLaunchKernelGGL(k1_gemm_scanA, dim3(NTILE), dim3(256), 0, stream,
                       x, Bbf, A_diag, steps, cs, Bu_g);
    hipLaunchKernelGGL(scan_comb_ks, dim3(BATCHN * 4), dim3(256), 0, stream,
                       cs, A_diag, steps);
    hipLaunchKernelGGL(k2_scan_gemm, dim3(NTILE), dim3(256), 0, stream,
                       Bu_g, x, A_diag, steps, Cbf, cs, Dv, out);
}